// Round 6
// baseline (173.630 us; speedup 1.0000x reference)
//
#include <hip/hip_runtime.h>
#include <float.h>

#define HH 640
#define WW 640
#define KTOP 6
#define CONF 0.3f
#define NTHR 256
#define XBANDS 3
#define XOUT 248
#define SEG 40                         // output rows per wave task
#define CHUNK 8                        // output rows per pipeline iteration
#define NITER (SEG / CHUNK)            // 5
#define YSEGS (HH / SEG)               // 16
#define TASKS_PER_B (XBANDS * YSEGS)   // 48
#define MENT (TASKS_PER_B * KTOP)      // 288
#define CAP 256

__device__ __forceinline__ float4 f4max(float4 a, float4 b) {
    return make_float4(fmaxf(a.x, b.x), fmaxf(a.y, b.y), fmaxf(a.z, b.z), fmaxf(a.w, b.w));
}

// ------- Kernel 1: pipelined register-streaming 9x9 NMS, per-wave top-6 -------
__global__ __launch_bounds__(NTHR) void peaks_kernel(const float* __restrict__ hm,
                                                     float* __restrict__ bscore,
                                                     int* __restrict__ bidx) {
    __shared__ float c_score[4][CAP];
    __shared__ int   c_idx[4][CAP];
    __shared__ int   c_cnt[4];

    const int t    = threadIdx.x;
    const int lane = t & 63;
    const int w    = t >> 6;
    const int task = blockIdx.x * 4 + w;                 // one 40x248 region per wave
    const int b    = task / TASKS_PER_B;
    const int rem  = task - b * TASKS_PER_B;
    const int ys   = rem / XBANDS;
    const int xb   = rem - ys * XBANDS;
    const int ybase = ys * SEG;
    const int x_raw = xb * XOUT - 4 + 4 * lane;
    const int xc    = min(max(x_raw, 0), WW - 4);
    const bool xok  = (x_raw >= 0) && (x_raw <= WW - 4);
    const bool vlane = (lane >= 1) && (lane <= 62) && xok;
    const float* colp = hm + (size_t)b * (HH * WW) + xc;
    const float4 NEG = make_float4(-FLT_MAX, -FLT_MAX, -FLT_MAX, -FLT_MAX);

    if (lane == 0) c_cnt[w] = 0;
    __syncthreads();                                     // only barrier in the kernel

    // clamped-row load: edge replication is exact for sliding-max w/ -inf SAME pad
    #define LDC(dst, yy) { int gy = (yy); \
        gy = gy < 0 ? 0 : (gy > HH - 1 ? HH - 1 : gy); \
        dst = *reinterpret_cast<const float4*>(colp + (size_t)gy * WW); }

    // horizontal 9-max via wave shuffles + peak detect for one output row
    #define PROCROW(m, c, gy_) { \
        const float w0 = __shfl_up(m.x, 1),  w1 = __shfl_up(m.y, 1); \
        const float w2 = __shfl_up(m.z, 1),  w3 = __shfl_up(m.w, 1); \
        const float w8 = __shfl_down(m.x, 1), w9 = __shfl_down(m.y, 1); \
        const float wA = __shfl_down(m.z, 1), wB = __shfl_down(m.w, 1); \
        const float hc = fmaxf(fmaxf(fmaxf(w3, m.x), fmaxf(m.y, m.z)), fmaxf(m.w, w8)); \
        const float ha = fmaxf(w1, w2); \
        const float hb = fmaxf(w9, wA); \
        const float h0 = fmaxf(hc, fmaxf(w0, ha)); \
        const float h1 = fmaxf(hc, fmaxf(ha, w9)); \
        const float h2 = fmaxf(hc, fmaxf(w2, hb)); \
        const float h3 = fmaxf(hc, fmaxf(hb, wB)); \
        if (vlane) { \
            const int base = (gy_) * WW + x_raw; \
            if (c.x > CONF && c.x >= h0) { int p_ = atomicAdd(&c_cnt[w], 1); if (p_ < CAP) { c_score[w][p_] = c.x; c_idx[w][p_] = base;     } } \
            if (c.y > CONF && c.y >= h1) { int p_ = atomicAdd(&c_cnt[w], 1); if (p_ < CAP) { c_score[w][p_] = c.y; c_idx[w][p_] = base + 1; } } \
            if (c.z > CONF && c.z >= h2) { int p_ = atomicAdd(&c_cnt[w], 1); if (p_ < CAP) { c_score[w][p_] = c.z; c_idx[w][p_] = base + 2; } } \
            if (c.w > CONF && c.w >= h3) { int p_ = atomicAdd(&c_cnt[w], 1); if (p_ < CAP) { c_score[w][p_] = c.w; c_idx[w][p_] = base + 3; } } \
        } \
    }

    // p[i] = row R-4+i, n[i] = row R+4+i (R = current chunk's first output row);
    // f[] = next chunk's n, issued BEFORE consuming n -> 2-deep load pipeline.
    float4 p[8], n[8], f[8];
    #pragma unroll
    for (int i = 0; i < 8; ++i) LDC(p[i], ybase - 4 + i)
    #pragma unroll
    for (int i = 0; i < 8; ++i) LDC(n[i], ybase + 4 + i)

    #pragma unroll
    for (int k = 0; k < NITER; ++k) {
        const int R = ybase + CHUNK * k;
        if (k < NITER - 1) {                       // compile-time branch (unrolled)
            #pragma unroll
            for (int i = 0; i < 8; ++i) LDC(f[i], R + 12 + i)
        }
        // vertical 9-windows over v[0..15]=p[0..7],n[0..7]: m_i = max(sufP[i], prefN[i])
        float4 S[8];
        S[7] = p[7];
        #pragma unroll
        for (int i = 6; i >= 0; --i) S[i] = f4max(p[i], S[i + 1]);
        float4 pref = n[0];
        #pragma unroll
        for (int i = 0; i < 8; ++i) {
            if (i > 0) pref = f4max(pref, n[i]);
            float4 m = f4max(S[i], pref);
            if (!xok) m = NEG;                     // invalid-x lanes feed -inf to neighbors
            const float4 c = (i < 4) ? p[4 + i] : n[i - 4];   // static after unroll
            PROCROW(m, c, R + i)
        }
        // rotate window
        if (k < NITER - 1) {
            #pragma unroll
            for (int i = 0; i < 8; ++i) { p[i] = n[i]; n[i] = f[i]; }
        }
    }

    // ---- per-wave top-6 from own LDS list (no barrier: wave-private slice) ----
    {
        const int cnt = min(c_cnt[w], CAP);
        float cs[4]; int ci[4];
        #pragma unroll
        for (int j = 0; j < 4; ++j) {
            const int pos = lane + 64 * j;
            const bool ok = pos < cnt;
            cs[j] = ok ? c_score[w][pos] : -2.0f;
            ci[j] = ok ? c_idx[w][pos]   : 0x7fffffff;
        }
        const int outbase = task * KTOP;
        #pragma unroll
        for (int k = 0; k < KTOP; ++k) {
            float bs = cs[0]; int bi = ci[0];
            #pragma unroll
            for (int j = 1; j < 4; ++j)
                if (cs[j] > bs || (cs[j] == bs && ci[j] < bi)) { bs = cs[j]; bi = ci[j]; }
            #pragma unroll
            for (int off = 32; off >= 1; off >>= 1) {
                const float os = __shfl_xor(bs, off);
                const int   oi = __shfl_xor(bi, off);
                if (os > bs || (os == bs && oi < bi)) { bs = os; bi = oi; }
            }
            if (lane == 0) { bscore[outbase + k] = bs; bidx[outbase + k] = bi; }
            #pragma unroll
            for (int j = 0; j < 4; ++j) if (ci[j] == bi) cs[j] = -3.0f;
        }
    }
}

// ------- Kernel 2: per-batch merge of 288 entries -> top-6 (1 wave) -------
__global__ __launch_bounds__(64) void topk_kernel(const float* __restrict__ bscore,
                                                  const int* __restrict__ bidx,
                                                  float* __restrict__ out,
                                                  int B) {
    const int t = threadIdx.x;   // 64 threads
    const int b = blockIdx.x;

    float s[5]; int id5[5];
    #pragma unroll
    for (int j = 0; j < 5; ++j) {
        const int e = t + 64 * j;
        const bool ok = e < MENT;
        s[j]   = ok ? bscore[b * MENT + e] : -9.0f;
        id5[j] = ok ? bidx[b * MENT + e]   : 0x7fffffff;
    }

    float my_s = -9.0f; int my_i = 0x7fffffff;
    #pragma unroll
    for (int k = 0; k < KTOP; ++k) {
        float bs = s[0]; int bi = id5[0];
        #pragma unroll
        for (int j = 1; j < 5; ++j)
            if (s[j] > bs || (s[j] == bs && id5[j] < bi)) { bs = s[j]; bi = id5[j]; }
        #pragma unroll
        for (int off = 32; off >= 1; off >>= 1) {
            const float os = __shfl_xor(bs, off);
            const int   oi = __shfl_xor(bi, off);
            if (os > bs || (os == bs && oi < bi)) { bs = os; bi = oi; }
        }
        if (t == k) { my_s = bs; my_i = bi; }   // thread k owns result k
        #pragma unroll
        for (int j = 0; j < 5; ++j) if (id5[j] == bi) s[j] = -9.0f;
    }

    if (t < KTOP) {
        const bool valid = (my_s > CONF) && (my_i >= 0) && (my_i < HH * WW);
        const int id = valid ? my_i : 0;
        const int xi = id % WW;
        const int yi = id / WW;
        const float px = valid ? xi * (1.0f / (WW - 1)) : -1.0f;
        const float py = valid ? yi * (1.0f / (HH - 1)) : -1.0f;
        out[(size_t)b * KTOP * 2 + t * 2 + 0] = px;
        out[(size_t)b * KTOP * 2 + t * 2 + 1] = py;
        out[(size_t)B * KTOP * 2 + (size_t)b * KTOP + t] = valid ? my_s : 0.0f;
    }
}

extern "C" void kernel_launch(void* const* d_in, const int* in_sizes, int n_in,
                              void* d_out, int out_size, void* d_ws, size_t ws_size,
                              hipStream_t stream) {
    const float* hm = (const float*)d_in[0];
    float* out = (float*)d_out;
    const int B = in_sizes[0] / (HH * WW);

    float* bscore = (float*)d_ws;
    int*   bidx   = (int*)((char*)d_ws + sizeof(float) * (size_t)B * MENT);

    const int nblocks = (B * TASKS_PER_B) / 4;   // 768: 4 wave-tasks per block
    peaks_kernel<<<nblocks, NTHR, 0, stream>>>(hm, bscore, bidx);
    topk_kernel<<<B, 64, 0, stream>>>(bscore, bidx, out, B);
}

// Round 8
// 165.372 us; speedup vs baseline: 1.0499x; 1.0499x over previous
//
#include <hip/hip_runtime.h>
#include <float.h>
#include <stdint.h>

#define HH 640
#define WW 640
#define KTOP 6
#define CONF 0.3f
#define NTHR 256
#define ROWS_W 16                       // output rows per wave
#define XBANDS 3
#define XOUT 248                        // output cols per band (lanes 1..62)
#define YWAVES (HH / ROWS_W)            // 40
#define TASKS_PER_B (XBANDS * YWAVES)   // 120
#define MENT (TASKS_PER_B * KTOP)       // 720
#define CAP 128

__device__ __forceinline__ float4 f4max(float4 a, float4 b) {
    return make_float4(fmaxf(a.x, b.x), fmaxf(a.y, b.y), fmaxf(a.z, b.z), fmaxf(a.w, b.w));
}

// ------- Kernel 1: asm-batched register-streaming 9x9 NMS, per-wave top-6 -------
__global__ __launch_bounds__(NTHR, 3) void peaks_kernel(const float* __restrict__ hm,
                                                        float* __restrict__ bscore,
                                                        int* __restrict__ bidx) {
    __shared__ float c_score[4][CAP];
    __shared__ int   c_idx[4][CAP];
    __shared__ int   c_cnt[4];

    const int t    = threadIdx.x;
    const int lane = t & 63;
    const int w    = t >> 6;
    const int task = blockIdx.x * 4 + w;          // one 16x248 region per wave
    const int b    = task / TASKS_PER_B;
    const int rem  = task - b * TASKS_PER_B;
    const int yw   = rem / XBANDS;
    const int xb   = rem - yw * XBANDS;
    const int ybase = yw * ROWS_W;
    const int x_raw = xb * XOUT - 4 + 4 * lane;
    const int xc    = min(max(x_raw, 0), WW - 4);
    const bool xok  = (x_raw >= 0) && (x_raw <= WW - 4);
    const bool vlane = (lane >= 1) && (lane <= 62) && xok;
    const float* colp = hm + (size_t)b * (HH * WW) + xc;
    const float4 NEG = make_float4(-FLT_MAX, -FLT_MAX, -FLT_MAX, -FLT_MAX);

    if (lane == 0) c_cnt[w] = 0;
    __syncthreads();

    // ---- 24 row loads via inline asm: forced to stay in flight together.
    // Row clamp = edge replication (exact for sliding max w/ -inf SAME padding).
    float4 r0, r1, r2, r3, r4, r5, r6, r7, r8, r9, r10, r11,
           r12, r13, r14, r15, r16, r17, r18, r19, r20, r21, r22, r23;
    #define LDA(i, dst) { int gy = ybase - 4 + (i); \
        gy = gy < 0 ? 0 : (gy > HH - 1 ? HH - 1 : gy); \
        const float* ap = colp + (size_t)gy * WW; \
        asm volatile("global_load_dwordx4 %0, %1, off" : "=&v"(dst) : "v"(ap)); }
    LDA(0,  r0)  LDA(1,  r1)  LDA(2,  r2)  LDA(3,  r3)
    LDA(4,  r4)  LDA(5,  r5)  LDA(6,  r6)  LDA(7,  r7)
    LDA(8,  r8)  LDA(9,  r9)  LDA(10, r10) LDA(11, r11)
    LDA(12, r12) LDA(13, r13) LDA(14, r14) LDA(15, r15)
    LDA(16, r16) LDA(17, r17) LDA(18, r18) LDA(19, r19)
    LDA(20, r20) LDA(21, r21) LDA(22, r22) LDA(23, r23)

    // horizontal 9-max via wave shuffles + peak detect for one output row
    #define PROCROW(m, c, gy_) { \
        const float w0 = __shfl_up(m.x, 1),  w1 = __shfl_up(m.y, 1); \
        const float w2 = __shfl_up(m.z, 1),  w3 = __shfl_up(m.w, 1); \
        const float w8 = __shfl_down(m.x, 1), w9 = __shfl_down(m.y, 1); \
        const float wA = __shfl_down(m.z, 1), wB = __shfl_down(m.w, 1); \
        const float hc = fmaxf(fmaxf(fmaxf(w3, m.x), fmaxf(m.y, m.z)), fmaxf(m.w, w8)); \
        const float ha = fmaxf(w1, w2); \
        const float hb = fmaxf(w9, wA); \
        const float h0 = fmaxf(hc, fmaxf(w0, ha)); \
        const float h1 = fmaxf(hc, fmaxf(ha, w9)); \
        const float h2 = fmaxf(hc, fmaxf(w2, hb)); \
        const float h3 = fmaxf(hc, fmaxf(hb, wB)); \
        if (vlane) { \
            const int base = (gy_) * WW + x_raw; \
            if (c.x > CONF && c.x >= h0) { int p_ = atomicAdd(&c_cnt[w], 1); if (p_ < CAP) { c_score[w][p_] = c.x; c_idx[w][p_] = base;     } } \
            if (c.y > CONF && c.y >= h1) { int p_ = atomicAdd(&c_cnt[w], 1); if (p_ < CAP) { c_score[w][p_] = c.y; c_idx[w][p_] = base + 1; } } \
            if (c.z > CONF && c.z >= h2) { int p_ = atomicAdd(&c_cnt[w], 1); if (p_ < CAP) { c_score[w][p_] = c.z; c_idx[w][p_] = base + 2; } } \
            if (c.w > CONF && c.w >= h3) { int p_ = atomicAdd(&c_cnt[w], 1); if (p_ < CAP) { c_score[w][p_] = c.w; c_idx[w][p_] = base + 3; } } \
        } \
    }

    // one vertical output row: m = max(S_suffix, prefix), masked for invalid-x lanes
    #define VROW(Sx, c, gy_) { \
        float4 m = f4max(Sx, pref); \
        if (!xok) m = NEG; \
        PROCROW(m, c, gy_) \
    }

    // ---- chunk A: output rows 0..7 (windows over r0..r15) ----
    asm volatile("s_waitcnt vmcnt(8)" ::: "memory");   // r0..r15 landed
    __builtin_amdgcn_sched_barrier(0);
    {
        float4 S7 = r7;
        float4 S6 = f4max(r6, S7), S5 = f4max(r5, S6), S4 = f4max(r4, S5);
        float4 S3 = f4max(r3, S4), S2 = f4max(r2, S3), S1 = f4max(r1, S2), S0 = f4max(r0, S1);
        float4 pref = r8;
        VROW(S0, r4,  ybase + 0)  pref = f4max(pref, r9);
        VROW(S1, r5,  ybase + 1)  pref = f4max(pref, r10);
        VROW(S2, r6,  ybase + 2)  pref = f4max(pref, r11);
        VROW(S3, r7,  ybase + 3)  pref = f4max(pref, r12);
        VROW(S4, r8,  ybase + 4)  pref = f4max(pref, r13);
        VROW(S5, r9,  ybase + 5)  pref = f4max(pref, r14);
        VROW(S6, r10, ybase + 6)  pref = f4max(pref, r15);
        VROW(S7, r11, ybase + 7)
    }

    // ---- chunk B: output rows 8..15 (windows over r8..r23) ----
    asm volatile("s_waitcnt vmcnt(0)" ::: "memory");   // r16..r23 landed
    __builtin_amdgcn_sched_barrier(0);
    {
        float4 S7 = r15;
        float4 S6 = f4max(r14, S7), S5 = f4max(r13, S6), S4 = f4max(r12, S5);
        float4 S3 = f4max(r11, S4), S2 = f4max(r10, S3), S1 = f4max(r9, S2), S0 = f4max(r8, S1);
        float4 pref = r16;
        VROW(S0, r12, ybase + 8)   pref = f4max(pref, r17);
        VROW(S1, r13, ybase + 9)   pref = f4max(pref, r18);
        VROW(S2, r14, ybase + 10)  pref = f4max(pref, r19);
        VROW(S3, r15, ybase + 11)  pref = f4max(pref, r20);
        VROW(S4, r16, ybase + 12)  pref = f4max(pref, r21);
        VROW(S5, r17, ybase + 13)  pref = f4max(pref, r22);
        VROW(S6, r18, ybase + 14)  pref = f4max(pref, r23);
        VROW(S7, r19, ybase + 15)
    }

    // ---- per-wave top-6 from own LDS list (wave-private: no barrier needed) ----
    {
        const int cnt = min(c_cnt[w], CAP);
        float cs0 = (lane      < cnt) ? c_score[w][lane]      : -2.0f;
        int   ci0 = (lane      < cnt) ? c_idx[w][lane]        : 0x7fffffff;
        float cs1 = (lane + 64 < cnt) ? c_score[w][lane + 64] : -2.0f;
        int   ci1 = (lane + 64 < cnt) ? c_idx[w][lane + 64]   : 0x7fffffff;
        const int outbase = task * KTOP;
        #pragma unroll
        for (int k = 0; k < KTOP; ++k) {
            float bs; int bi;
            if (cs0 > cs1 || (cs0 == cs1 && ci0 < ci1)) { bs = cs0; bi = ci0; }
            else                                        { bs = cs1; bi = ci1; }
            #pragma unroll
            for (int off = 32; off >= 1; off >>= 1) {
                const float os = __shfl_xor(bs, off);
                const int   oi = __shfl_xor(bi, off);
                if (os > bs || (os == bs && oi < bi)) { bs = os; bi = oi; }
            }
            if (lane == 0) { bscore[outbase + k] = bs; bidx[outbase + k] = bi; }
            if (ci0 == bi) cs0 = -3.0f;
            if (ci1 == bi) cs1 = -3.0f;
        }
    }
}

// ------- Kernel 2: per-batch merge of 720 entries -> top-6 (1 wave) -------
__global__ __launch_bounds__(64) void topk_kernel(const float* __restrict__ bscore,
                                                  const int* __restrict__ bidx,
                                                  float* __restrict__ out,
                                                  int B) {
    const int t = threadIdx.x;   // 64 threads
    const int b = blockIdx.x;

    float s[12]; int id[12];
    #pragma unroll
    for (int j = 0; j < 12; ++j) {
        const int e = t + 64 * j;
        const bool ok = e < MENT;
        s[j]  = ok ? bscore[b * MENT + e] : -9.0f;
        id[j] = ok ? bidx[b * MENT + e]   : 0x7fffffff;
    }

    float my_s = -9.0f; int my_i = 0x7fffffff;
    #pragma unroll
    for (int k = 0; k < KTOP; ++k) {
        float bs = s[0]; int bi = id[0];
        #pragma unroll
        for (int j = 1; j < 12; ++j)
            if (s[j] > bs || (s[j] == bs && id[j] < bi)) { bs = s[j]; bi = id[j]; }
        #pragma unroll
        for (int off = 32; off >= 1; off >>= 1) {
            const float os = __shfl_xor(bs, off);
            const int   oi = __shfl_xor(bi, off);
            if (os > bs || (os == bs && oi < bi)) { bs = os; bi = oi; }
        }
        if (t == k) { my_s = bs; my_i = bi; }   // thread k owns result k
        #pragma unroll
        for (int j = 0; j < 12; ++j) if (id[j] == bi) s[j] = -9.0f;
    }

    if (t < KTOP) {
        const bool valid = (my_s > CONF) && (my_i >= 0) && (my_i < HH * WW);
        const int idv = valid ? my_i : 0;
        const int xi = idv % WW;
        const int yi = idv / WW;
        const float px = valid ? xi * (1.0f / (WW - 1)) : -1.0f;
        const float py = valid ? yi * (1.0f / (HH - 1)) : -1.0f;
        out[(size_t)b * KTOP * 2 + t * 2 + 0] = px;
        out[(size_t)b * KTOP * 2 + t * 2 + 1] = py;
        out[(size_t)B * KTOP * 2 + (size_t)b * KTOP + t] = valid ? my_s : 0.0f;
    }
}

extern "C" void kernel_launch(void* const* d_in, const int* in_sizes, int n_in,
                              void* d_out, int out_size, void* d_ws, size_t ws_size,
                              hipStream_t stream) {
    const float* hm = (const float*)d_in[0];
    float* out = (float*)d_out;
    const int B = in_sizes[0] / (HH * WW);

    float* bscore = (float*)d_ws;
    int*   bidx   = (int*)((char*)d_ws + sizeof(float) * (size_t)B * MENT);

    const int nblocks = (B * TASKS_PER_B) / 4;   // 1920: 4 wave-tasks per block
    peaks_kernel<<<nblocks, NTHR, 0, stream>>>(hm, bscore, bidx);
    topk_kernel<<<B, 64, 0, stream>>>(bscore, bidx, out, B);
}

// Round 9
// 163.701 us; speedup vs baseline: 1.0607x; 1.0102x over previous
//
#include <hip/hip_runtime.h>
#include <float.h>
#include <stdint.h>

#define HH 640
#define WW 640
#define KTOP 6
#define CONF 0.3f
#define NTHR 256
#define ROWS_W 16                       // output rows per wave
#define XBANDS 3
#define XOUT 248                        // output cols per band (lanes 1..62)
#define YWAVES (HH / ROWS_W)            // 40
#define TASKS_PER_B (XBANDS * YWAVES)   // 120
#define MENT (TASKS_PER_B * KTOP)       // 720
#define CAP 128

__device__ __forceinline__ float4 f4max(float4 a, float4 b) {
    return make_float4(fmaxf(a.x, b.x), fmaxf(a.y, b.y), fmaxf(a.z, b.z), fmaxf(a.w, b.w));
}

// DPP wave-wide lane shifts: pure VALU, no LDS pipe. old = -inf bits so the
// wave-edge lane receives the max-identity.
// WAVE_SHR1 (0x138): lane i <- lane i-1  (== __shfl_up(x,1))
// WAVE_SHL1 (0x130): lane i <- lane i+1  (== __shfl_down(x,1))
__device__ __forceinline__ float dpp_up(float v) {
    return __int_as_float(__builtin_amdgcn_update_dpp(
        (int)0xFF800000, __float_as_int(v), 0x138, 0xF, 0xF, false));
}
__device__ __forceinline__ float dpp_dn(float v) {
    return __int_as_float(__builtin_amdgcn_update_dpp(
        (int)0xFF800000, __float_as_int(v), 0x130, 0xF, 0xF, false));
}

// ------- Kernel 1: asm-batched loads + DPP horizontal 9-max, per-wave top-6 -------
__global__ __launch_bounds__(NTHR, 3) void peaks_kernel(const float* __restrict__ hm,
                                                        float* __restrict__ bscore,
                                                        int* __restrict__ bidx) {
    __shared__ float c_score[4][CAP];
    __shared__ int   c_idx[4][CAP];
    __shared__ int   c_cnt[4];

    const int t    = threadIdx.x;
    const int lane = t & 63;
    const int w    = t >> 6;
    const int task = blockIdx.x * 4 + w;          // one 16x248 region per wave
    const int b    = task / TASKS_PER_B;
    const int rem  = task - b * TASKS_PER_B;
    const int yw   = rem / XBANDS;
    const int xb   = rem - yw * XBANDS;
    const int ybase = yw * ROWS_W;
    const int x_raw = xb * XOUT - 4 + 4 * lane;
    const int xc    = min(max(x_raw, 0), WW - 4);
    const bool xok  = (x_raw >= 0) && (x_raw <= WW - 4);
    const bool vlane = (lane >= 1) && (lane <= 62) && xok;
    const float* colp = hm + (size_t)b * (HH * WW) + xc;
    const float4 NEG = make_float4(-FLT_MAX, -FLT_MAX, -FLT_MAX, -FLT_MAX);

    if (lane == 0) c_cnt[w] = 0;   // wave-private: no barrier needed anywhere

    // ---- 24 row loads via inline asm: pinned in flight together.
    // Row clamp = edge replication (exact for sliding max w/ -inf SAME padding).
    float4 r0, r1, r2, r3, r4, r5, r6, r7, r8, r9, r10, r11,
           r12, r13, r14, r15, r16, r17, r18, r19, r20, r21, r22, r23;
    #define LDA(i, dst) { int gy = ybase - 4 + (i); \
        gy = gy < 0 ? 0 : (gy > HH - 1 ? HH - 1 : gy); \
        const float* ap = colp + (size_t)gy * WW; \
        asm volatile("global_load_dwordx4 %0, %1, off" : "=&v"(dst) : "v"(ap)); }
    LDA(0,  r0)  LDA(1,  r1)  LDA(2,  r2)  LDA(3,  r3)
    LDA(4,  r4)  LDA(5,  r5)  LDA(6,  r6)  LDA(7,  r7)
    LDA(8,  r8)  LDA(9,  r9)  LDA(10, r10) LDA(11, r11)
    LDA(12, r12) LDA(13, r13) LDA(14, r14) LDA(15, r15)
    LDA(16, r16) LDA(17, r17) LDA(18, r18) LDA(19, r19)
    LDA(20, r20) LDA(21, r21) LDA(22, r22) LDA(23, r23)

    // horizontal 9-max via DPP + peak detect for one output row.
    // Windows (lane cols x..x+3): left lane supplies w0..w3, right lane w8..wB.
    //   hc = max(w3, m.x..m.w, w8);  ha = max(w1,w2) = up(max(m.y,m.z));
    //   hb = max(w9,wA) = dn(max(m.y,m.z))
    #define PROCROW(m, c, gy_) { \
        const float a_ = fmaxf(m.y, m.z); \
        const float w0 = dpp_up(m.x), ha = dpp_up(a_), w2 = dpp_up(m.z), w3 = dpp_up(m.w); \
        const float w8 = dpp_dn(m.x), w9 = dpp_dn(m.y), hb = dpp_dn(a_), wB = dpp_dn(m.w); \
        const float mc = fmaxf(fmaxf(m.x, a_), m.w); \
        const float hc = fmaxf(fmaxf(w3, mc), w8); \
        const float h0 = fmaxf(hc, fmaxf(w0, ha)); \
        const float h1 = fmaxf(hc, fmaxf(ha, w9)); \
        const float h2 = fmaxf(hc, fmaxf(w2, hb)); \
        const float h3 = fmaxf(hc, fmaxf(hb, wB)); \
        if (vlane) { \
            const int base = (gy_) * WW + x_raw; \
            if (c.x > CONF && c.x >= h0) { int p_ = atomicAdd(&c_cnt[w], 1); if (p_ < CAP) { c_score[w][p_] = c.x; c_idx[w][p_] = base;     } } \
            if (c.y > CONF && c.y >= h1) { int p_ = atomicAdd(&c_cnt[w], 1); if (p_ < CAP) { c_score[w][p_] = c.y; c_idx[w][p_] = base + 1; } } \
            if (c.z > CONF && c.z >= h2) { int p_ = atomicAdd(&c_cnt[w], 1); if (p_ < CAP) { c_score[w][p_] = c.z; c_idx[w][p_] = base + 2; } } \
            if (c.w > CONF && c.w >= h3) { int p_ = atomicAdd(&c_cnt[w], 1); if (p_ < CAP) { c_score[w][p_] = c.w; c_idx[w][p_] = base + 3; } } \
        } \
    }

    // one vertical output row: m = max(S_suffix, prefix), masked for invalid-x lanes
    #define VROW(Sx, c, gy_) { \
        float4 m = f4max(Sx, pref); \
        if (!xok) m = NEG; \
        PROCROW(m, c, gy_) \
    }

    // ---- chunk A: output rows 0..7 (windows over r0..r15) ----
    asm volatile("s_waitcnt vmcnt(8)" ::: "memory");   // r0..r15 landed
    __builtin_amdgcn_sched_barrier(0);
    {
        float4 S7 = r7;
        float4 S6 = f4max(r6, S7), S5 = f4max(r5, S6), S4 = f4max(r4, S5);
        float4 S3 = f4max(r3, S4), S2 = f4max(r2, S3), S1 = f4max(r1, S2), S0 = f4max(r0, S1);
        float4 pref = r8;
        VROW(S0, r4,  ybase + 0)  pref = f4max(pref, r9);
        VROW(S1, r5,  ybase + 1)  pref = f4max(pref, r10);
        VROW(S2, r6,  ybase + 2)  pref = f4max(pref, r11);
        VROW(S3, r7,  ybase + 3)  pref = f4max(pref, r12);
        VROW(S4, r8,  ybase + 4)  pref = f4max(pref, r13);
        VROW(S5, r9,  ybase + 5)  pref = f4max(pref, r14);
        VROW(S6, r10, ybase + 6)  pref = f4max(pref, r15);
        VROW(S7, r11, ybase + 7)
    }

    // ---- chunk B: output rows 8..15 (windows over r8..r23) ----
    asm volatile("s_waitcnt vmcnt(0)" ::: "memory");   // r16..r23 landed
    __builtin_amdgcn_sched_barrier(0);
    {
        float4 S7 = r15;
        float4 S6 = f4max(r14, S7), S5 = f4max(r13, S6), S4 = f4max(r12, S5);
        float4 S3 = f4max(r11, S4), S2 = f4max(r10, S3), S1 = f4max(r9, S2), S0 = f4max(r8, S1);
        float4 pref = r16;
        VROW(S0, r12, ybase + 8)   pref = f4max(pref, r17);
        VROW(S1, r13, ybase + 9)   pref = f4max(pref, r18);
        VROW(S2, r14, ybase + 10)  pref = f4max(pref, r19);
        VROW(S3, r15, ybase + 11)  pref = f4max(pref, r20);
        VROW(S4, r16, ybase + 12)  pref = f4max(pref, r21);
        VROW(S5, r17, ybase + 13)  pref = f4max(pref, r22);
        VROW(S6, r18, ybase + 14)  pref = f4max(pref, r23);
        VROW(S7, r19, ybase + 15)
    }

    // ---- per-wave top-6 from own LDS list (wave-private: no barrier needed) ----
    {
        const int cnt = min(c_cnt[w], CAP);
        float cs0 = (lane      < cnt) ? c_score[w][lane]      : -2.0f;
        int   ci0 = (lane      < cnt) ? c_idx[w][lane]        : 0x7fffffff;
        float cs1 = (lane + 64 < cnt) ? c_score[w][lane + 64] : -2.0f;
        int   ci1 = (lane + 64 < cnt) ? c_idx[w][lane + 64]   : 0x7fffffff;
        const int outbase = task * KTOP;
        #pragma unroll
        for (int k = 0; k < KTOP; ++k) {
            float bs; int bi;
            if (cs0 > cs1 || (cs0 == cs1 && ci0 < ci1)) { bs = cs0; bi = ci0; }
            else                                        { bs = cs1; bi = ci1; }
            #pragma unroll
            for (int off = 32; off >= 1; off >>= 1) {
                const float os = __shfl_xor(bs, off);
                const int   oi = __shfl_xor(bi, off);
                if (os > bs || (os == bs && oi < bi)) { bs = os; bi = oi; }
            }
            if (lane == 0) { bscore[outbase + k] = bs; bidx[outbase + k] = bi; }
            if (ci0 == bi) cs0 = -3.0f;
            if (ci1 == bi) cs1 = -3.0f;
        }
    }
}

// ------- Kernel 2: per-batch merge of 720 entries -> top-6 (1 wave) -------
__global__ __launch_bounds__(64) void topk_kernel(const float* __restrict__ bscore,
                                                  const int* __restrict__ bidx,
                                                  float* __restrict__ out,
                                                  int B) {
    const int t = threadIdx.x;   // 64 threads
    const int b = blockIdx.x;

    float s[12]; int id[12];
    #pragma unroll
    for (int j = 0; j < 12; ++j) {
        const int e = t + 64 * j;
        const bool ok = e < MENT;
        s[j]  = ok ? bscore[b * MENT + e] : -9.0f;
        id[j] = ok ? bidx[b * MENT + e]   : 0x7fffffff;
    }

    float my_s = -9.0f; int my_i = 0x7fffffff;
    #pragma unroll
    for (int k = 0; k < KTOP; ++k) {
        float bs = s[0]; int bi = id[0];
        #pragma unroll
        for (int j = 1; j < 12; ++j)
            if (s[j] > bs || (s[j] == bs && id[j] < bi)) { bs = s[j]; bi = id[j]; }
        #pragma unroll
        for (int off = 32; off >= 1; off >>= 1) {
            const float os = __shfl_xor(bs, off);
            const int   oi = __shfl_xor(bi, off);
            if (os > bs || (os == bs && oi < bi)) { bs = os; bi = oi; }
        }
        if (t == k) { my_s = bs; my_i = bi; }   // thread k owns result k
        #pragma unroll
        for (int j = 0; j < 12; ++j) if (id[j] == bi) s[j] = -9.0f;
    }

    if (t < KTOP) {
        const bool valid = (my_s > CONF) && (my_i >= 0) && (my_i < HH * WW);
        const int idv = valid ? my_i : 0;
        const int xi = idv % WW;
        const int yi = idv / WW;
        const float px = valid ? xi * (1.0f / (WW - 1)) : -1.0f;
        const float py = valid ? yi * (1.0f / (HH - 1)) : -1.0f;
        out[(size_t)b * KTOP * 2 + t * 2 + 0] = px;
        out[(size_t)b * KTOP * 2 + t * 2 + 1] = py;
        out[(size_t)B * KTOP * 2 + (size_t)b * KTOP + t] = valid ? my_s : 0.0f;
    }
}

extern "C" void kernel_launch(void* const* d_in, const int* in_sizes, int n_in,
                              void* d_out, int out_size, void* d_ws, size_t ws_size,
                              hipStream_t stream) {
    const float* hm = (const float*)d_in[0];
    float* out = (float*)d_out;
    const int B = in_sizes[0] / (HH * WW);

    float* bscore = (float*)d_ws;
    int*   bidx   = (int*)((char*)d_ws + sizeof(float) * (size_t)B * MENT);

    const int nblocks = (B * TASKS_PER_B) / 4;   // 1920: 4 wave-tasks per block
    peaks_kernel<<<nblocks, NTHR, 0, stream>>>(hm, bscore, bidx);
    topk_kernel<<<B, 64, 0, stream>>>(bscore, bidx, out, B);
}